// Round 1
// baseline (137.329 us; speedup 1.0000x reference)
//
#include <hip/hip_runtime.h>

#define N_FEAT 2048
#define ORDER 8
#define BATCH 8192
#define BLOCK 256

// Kernel 1: normalize each of the 8 reflection vectors (row-wise L2) into ws.
__global__ __launch_bounds__(BLOCK) void normalize_v_kernel(
    const float* __restrict__ v, float* __restrict__ vn) {
    const int row = blockIdx.x;          // 0..ORDER-1
    const int tid = threadIdx.x;         // 0..255
    const float* vr = v + (size_t)row * N_FEAT;

    float ss = 0.f;
    #pragma unroll
    for (int k = tid; k < N_FEAT; k += BLOCK) {
        float a = vr[k];
        ss += a * a;
    }
    // wave (64-lane) reduce
    #pragma unroll
    for (int o = 32; o > 0; o >>= 1) ss += __shfl_down(ss, o, 64);
    __shared__ float red[4];
    const int lane = tid & 63, wid = tid >> 6;
    if (lane == 0) red[wid] = ss;
    __syncthreads();
    const float tot = red[0] + red[1] + red[2] + red[3];
    const float inv = 1.0f / sqrtf(tot);
    #pragma unroll
    for (int k = tid; k < N_FEAT; k += BLOCK) {
        vn[(size_t)row * N_FEAT + k] = vr[k] * inv;
    }
}

// Kernel 2: one block per batch row. z = x_row; apply 8 Householder
// reflections z -= 2 (z . vn_i) vn_i; then y = z * d + bias.
__global__ __launch_bounds__(BLOCK) void orth_apply_kernel(
    const float* __restrict__ x, const float* __restrict__ vn,
    const float* __restrict__ d, const float* __restrict__ bias,
    float* __restrict__ y) {
    const int row = blockIdx.x;          // 0..BATCH-1
    const int tid = threadIdx.x;         // 0..255
    const size_t base = (size_t)row * N_FEAT;

    // Row in registers: two contiguous float4 chunks (coalesced 16B/lane).
    float4 z0 = *(const float4*)(x + base + tid * 4);
    float4 z1 = *(const float4*)(x + base + 1024 + tid * 4);

    __shared__ float red[4];
    const int lane = tid & 63, wid = tid >> 6;

    #pragma unroll
    for (int i = 0; i < ORDER; ++i) {
        const float* vr = vn + (size_t)i * N_FEAT;
        const float4 a0 = *(const float4*)(vr + tid * 4);
        const float4 a1 = *(const float4*)(vr + 1024 + tid * 4);

        float p = z0.x * a0.x + z0.y * a0.y + z0.z * a0.z + z0.w * a0.w
                + z1.x * a1.x + z1.y * a1.y + z1.z * a1.z + z1.w * a1.w;
        #pragma unroll
        for (int o = 32; o > 0; o >>= 1) p += __shfl_down(p, o, 64);

        __syncthreads();                 // protect red[] vs previous iter reads
        if (lane == 0) red[wid] = p;
        __syncthreads();
        const float s = -2.0f * (red[0] + red[1] + red[2] + red[3]);

        z0.x += s * a0.x; z0.y += s * a0.y; z0.z += s * a0.z; z0.w += s * a0.w;
        z1.x += s * a1.x; z1.y += s * a1.y; z1.z += s * a1.z; z1.w += s * a1.w;
    }

    // Epilogue: column scale by d, add bias. (out==in==2048, so full width.)
    const float4 d0 = *(const float4*)(d + tid * 4);
    const float4 d1 = *(const float4*)(d + 1024 + tid * 4);
    const float4 b0 = *(const float4*)(bias + tid * 4);
    const float4 b1 = *(const float4*)(bias + 1024 + tid * 4);

    float4 o0, o1;
    o0.x = z0.x * d0.x + b0.x; o0.y = z0.y * d0.y + b0.y;
    o0.z = z0.z * d0.z + b0.z; o0.w = z0.w * d0.w + b0.w;
    o1.x = z1.x * d1.x + b1.x; o1.y = z1.y * d1.y + b1.y;
    o1.z = z1.z * d1.z + b1.z; o1.w = z1.w * d1.w + b1.w;

    *(float4*)(y + base + tid * 4) = o0;
    *(float4*)(y + base + 1024 + tid * 4) = o1;
}

extern "C" void kernel_launch(void* const* d_in, const int* in_sizes, int n_in,
                              void* d_out, int out_size, void* d_ws, size_t ws_size,
                              hipStream_t stream) {
    const float* x    = (const float*)d_in[0];  // [8192, 2048]
    const float* v    = (const float*)d_in[1];  // [8, 2048]
    const float* d    = (const float*)d_in[2];  // [2048]
    const float* bias = (const float*)d_in[3];  // [2048]
    float* y = (float*)d_out;                   // [8192, 2048]
    float* vn = (float*)d_ws;                   // [8, 2048] normalized vectors

    normalize_v_kernel<<<ORDER, BLOCK, 0, stream>>>(v, vn);
    orth_apply_kernel<<<BATCH, BLOCK, 0, stream>>>(x, vn, d, bias, y);
}